// Round 7
// baseline (142.538 us; speedup 1.0000x reference)
//
#include <hip/hip_runtime.h>
#include <cstdint>
#include <cstddef>

#define DM 1024
#define NHEAD 16
#define DKH 64
#define SEQLEN 2048
#define NBATCH 2
#define MTOT (NBATCH * SEQLEN)  // 4096

typedef __attribute__((ext_vector_type(8))) short bf16x8;
typedef __attribute__((ext_vector_type(4))) float f32x4;
typedef __attribute__((ext_vector_type(16))) float f32x16;
typedef __attribute__((ext_vector_type(2))) unsigned int u32x2;

// (1/sqrt(Dk)) * log2(e): folded into Q projection; attn softmax uses exp2.
#define QSCALE 0.18033688011112042f

__device__ __forceinline__ uint16_t f2bf(float f) {
  uint32_t x = __float_as_uint(f);
  uint32_t r = x + 0x7FFFu + ((x >> 16) & 1u);  // RNE; inputs finite
  return (uint16_t)(r >> 16);
}

__device__ __forceinline__ uint32_t cvtpk(float a, float b) {
  uint32_t r;
  asm("v_cvt_pk_bf16_f32 %0, %1, %2" : "=v"(r) : "v"(a), "v"(b));
  return r;
}

__device__ __forceinline__ float exp2_fast(float x) {
  float r;
  asm("v_exp_f32 %0, %1" : "=v"(r) : "v"(x));
  return r;
}

__device__ __forceinline__ float max3f(float a, float b, float c) {
  float r;
  asm("v_max3_f32 %0, %1, %2, %3" : "=v"(r) : "v"(a), "v"(b), "v"(c));
  return r;
}

__device__ __forceinline__ void gload_lds16(const void* g, void* l) {
  __builtin_amdgcn_global_load_lds(
      (const __attribute__((address_space(1))) void*)g,
      (__attribute__((address_space(3))) void*)l, 16, 0, 0);
}

// Swizzle: 16B-slot XOR (bits 4-6) so 32-row column reads spread over 8 slots.
__device__ __forceinline__ int fsw(int r) { return ((r + (r >> 3)) & 7) << 4; }

// ---- fused fp32 -> bf16 convert over 7 regions in one launch ----
struct CvtArgs {
  const float* src[7];
  uint16_t* dst[7];
  int end4[7];  // cumulative float4 counts
};

__global__ void cvt_all_kernel(CvtArgs a) {
  int i = blockIdx.x * blockDim.x + threadIdx.x;
  int r = 0;
#pragma unroll
  for (int j = 0; j < 7; ++j)
    if (i >= a.end4[j]) r = j + 1;
  if (r >= 7) return;
  int local = i - (r == 0 ? 0 : a.end4[r - 1]);
  float4 v = reinterpret_cast<const float4*>(a.src[r])[local];
  uint64_t p = (uint64_t)f2bf(v.x) | ((uint64_t)f2bf(v.y) << 16) |
               ((uint64_t)f2bf(v.z) << 32) | ((uint64_t)f2bf(v.w) << 48);
  reinterpret_cast<uint64_t*>(a.dst[r])[local] = p;
}

// Stage one 128x64 A-tile + 128x64 B-tile (32 KiB) into LDS buffer `buf`.
// T3-min 2-phase: called for tile t+1 BEFORE computing tile t.
__device__ __forceinline__ void gemm_stage(const uint16_t* __restrict__ A,
                                           const uint16_t* __restrict__ Bt,
                                           int brow, int bcol, int k0,
                                           char* smem, int buf, int wave, int lane) {
#pragma unroll
  for (int t = 0; t < 8; ++t) {
    const int o = t * 4096 + wave * 1024 + lane * 16;
    const uint16_t* g;
    if (t < 4) {
      const int row = o >> 7, kk = (o & 127) >> 1;
      g = A + (size_t)(brow + row) * DM + (k0 + kk);
    } else {
      const int o2 = o - 16384;
      const int row = o2 >> 7, kk = (o2 & 127) >> 1;
      g = Bt + (size_t)(bcol + row) * DM + (k0 + kk);
    }
    gload_lds16(g, smem + buf * 32768 + t * 4096 + wave * 1024);
  }
}

// ---- fused QKV projection GEMM (2-phase double-buffered) ----
// grid (M/128, 24): blockIdx.y>>3 selects projection (0=Q,1=K,2=V).
// C = A @ W^T + b; Q scaled by QSCALE; V written transposed to [b,h,d,s].
__global__ __launch_bounds__(256)
void gemm_qkv(const uint16_t* __restrict__ xq, const uint16_t* __restrict__ xk,
              const uint16_t* __restrict__ xv, const uint16_t* __restrict__ wqkv,
              const float* __restrict__ bqp, const float* __restrict__ bkp,
              const float* __restrict__ bvp, uint16_t* __restrict__ Qp,
              uint16_t* __restrict__ Kp, uint16_t* __restrict__ VTp) {
  __shared__ uint16_t smem[2 * 2 * 128 * 64];  // 64 KiB: 2 bufs x (A|B)
  const int tid = threadIdx.x;
  const int wave = tid >> 6, lane = tid & 63;
  const int l15 = lane & 15, l4 = lane >> 4;
  const int proj = blockIdx.y >> 3;
  const int brow = blockIdx.x * 128, bcol = (blockIdx.y & 7) * 128;
  const int wr = (wave >> 1) * 64, wc = (wave & 1) * 64;
  const uint16_t* A = proj == 0 ? xq : proj == 1 ? xk : xv;
  const uint16_t* Bt = wqkv + (size_t)proj * DM * DM;
  const float* bias = proj == 0 ? bqp : proj == 1 ? bkp : bvp;

  const f32x4 fzero = {0.f, 0.f, 0.f, 0.f};
  f32x4 acc[4][4];
#pragma unroll
  for (int m = 0; m < 4; ++m)
#pragma unroll
    for (int n = 0; n < 4; ++n) acc[m][n] = fzero;

  gemm_stage(A, Bt, brow, bcol, 0, (char*)smem, 0, wave, lane);
  int cur = 0;
  for (int k0 = 0; k0 < DM; k0 += 64) {
    __syncthreads();  // loads for buf[cur] drained; buf[cur^1] free of readers
    if (k0 + 64 < DM)
      gemm_stage(A, Bt, brow, bcol, k0 + 64, (char*)smem, cur ^ 1, wave, lane);
    const uint16_t* At = smem + cur * 16384;
    const uint16_t* Bs = At + 8192;
#pragma unroll
    for (int ks = 0; ks < 2; ++ks) {
      bf16x8 a[4], b[4];
#pragma unroll
      for (int m = 0; m < 4; ++m)
        a[m] = *(const bf16x8*)(At + (wr + m * 16 + l15) * 64 + ks * 32 + l4 * 8);
#pragma unroll
      for (int n = 0; n < 4; ++n)
        b[n] = *(const bf16x8*)(Bs + (wc + n * 16 + l15) * 64 + ks * 32 + l4 * 8);
#pragma unroll
      for (int m = 0; m < 4; ++m)
#pragma unroll
        for (int n = 0; n < 4; ++n)
          acc[m][n] = __builtin_amdgcn_mfma_f32_16x16x32_bf16(a[m], b[n], acc[m][n], 0, 0, 0);
    }
    cur ^= 1;
  }

  const float scale = proj == 0 ? QSCALE : 1.0f;
  uint16_t* dstQK = proj == 0 ? Qp : Kp;
#pragma unroll
  for (int m = 0; m < 4; ++m) {
#pragma unroll
    for (int n = 0; n < 4; ++n) {
      const int gcol = bcol + wc + n * 16 + l15;
      const float bv = bias[gcol];
      if (proj == 2) {
        // V^T: element (s=grow, col=gcol) -> VT[(b*NHEAD+h)*DKH + d][s].
        const int grow0 = brow + wr + m * 16 + l4 * 4;
        const int b_ = grow0 >> 11, s_ = grow0 & 2047;
        const int h_ = gcol >> 6, d_ = gcol & 63;
        uint16_t* dst = VTp + ((size_t)((b_ * NHEAD + h_) * DKH + d_)) * SEQLEN + s_;
        uint64_t pk = (uint64_t)f2bf(acc[m][n][0] + bv) |
                      ((uint64_t)f2bf(acc[m][n][1] + bv) << 16) |
                      ((uint64_t)f2bf(acc[m][n][2] + bv) << 32) |
                      ((uint64_t)f2bf(acc[m][n][3] + bv) << 48);
        *(uint64_t*)dst = pk;
      } else {
#pragma unroll
        for (int r = 0; r < 4; ++r) {
          const int grow = brow + wr + m * 16 + l4 * 4 + r;
          dstQK[(size_t)grow * DM + gcol] = f2bf((acc[m][n][r] + bv) * scale);
        }
      }
    }
  }
}

// ---- output projection GEMM (f32 out, 2-phase double-buffered) ----
__global__ __launch_bounds__(256)
void gemm_out(const uint16_t* __restrict__ A, const uint16_t* __restrict__ Bt,
              const float* __restrict__ bias, float* __restrict__ C) {
  __shared__ uint16_t smem[2 * 2 * 128 * 64];  // 64 KiB
  const int tid = threadIdx.x;
  const int wave = tid >> 6, lane = tid & 63;
  const int l15 = lane & 15, l4 = lane >> 4;
  const int brow = blockIdx.x * 128, bcol = blockIdx.y * 128;
  const int wr = (wave >> 1) * 64, wc = (wave & 1) * 64;

  const f32x4 fzero = {0.f, 0.f, 0.f, 0.f};
  f32x4 acc[4][4];
#pragma unroll
  for (int m = 0; m < 4; ++m)
#pragma unroll
    for (int n = 0; n < 4; ++n) acc[m][n] = fzero;

  gemm_stage(A, Bt, brow, bcol, 0, (char*)smem, 0, wave, lane);
  int cur = 0;
  for (int k0 = 0; k0 < DM; k0 += 64) {
    __syncthreads();
    if (k0 + 64 < DM)
      gemm_stage(A, Bt, brow, bcol, k0 + 64, (char*)smem, cur ^ 1, wave, lane);
    const uint16_t* At = smem + cur * 16384;
    const uint16_t* Bs = At + 8192;
#pragma unroll
    for (int ks = 0; ks < 2; ++ks) {
      bf16x8 a[4], b[4];
#pragma unroll
      for (int m = 0; m < 4; ++m)
        a[m] = *(const bf16x8*)(At + (wr + m * 16 + l15) * 64 + ks * 32 + l4 * 8);
#pragma unroll
      for (int n = 0; n < 4; ++n)
        b[n] = *(const bf16x8*)(Bs + (wc + n * 16 + l15) * 64 + ks * 32 + l4 * 8);
#pragma unroll
      for (int m = 0; m < 4; ++m)
#pragma unroll
        for (int n = 0; n < 4; ++n)
          acc[m][n] = __builtin_amdgcn_mfma_f32_16x16x32_bf16(a[m], b[n], acc[m][n], 0, 0, 0);
    }
    cur ^= 1;
  }

#pragma unroll
  for (int m = 0; m < 4; ++m) {
#pragma unroll
    for (int n = 0; n < 4; ++n) {
      const int gcol = bcol + wc + n * 16 + l15;
      const float bv = bias[gcol];
#pragma unroll
      for (int r = 0; r < 4; ++r) {
        const int grow = brow + wr + m * 16 + l4 * 4 + r;
        C[(size_t)grow * DM + gcol] = acc[m][n][r] + bv;
      }
    }
  }
}

// ---- flash attention, 32x32 MFMA, in-register P, KVBLK=128 ----
// Block = (b, h, 128 q-rows); 4 waves x 32 q-rows. KV tile = 128 rows.
// Swapped QK^T: mfma(K, Q) -> S^T. Softmax per-lane (q = lane&31).
// P -> PV B-fragments in-register via cvt_pk + permlane32_swap (T12).
// Row-sum l via mfma(ones, P_frag, lacc). sacc chains start from a
// never-written zero16 C-operand (no per-tile zero-init VALU).
// LDS per buffer: K 128x[128B] at +0 (16KB), V^T 64x[256B] at +16KB.
__device__ __forceinline__ void stage_kv(const uint16_t* __restrict__ Kg,
                                         const uint16_t* __restrict__ Vg,
                                         char* buf, int wave, int lane) {
#pragma unroll
  for (int i = 0; i < 4; ++i) {
    const int c = wave * 4 + i;  // 1 KiB chunk index, 0..15
    const int off = c * 1024 + lane * 16;
    {  // K: row = off>>7 (128B rows), swizzled source
      const int row = off >> 7;
      const int esw = ((off & 127) ^ fsw(row)) >> 1;
      gload_lds16(Kg + (size_t)row * DM + esw, buf + c * 1024);
    }
    {  // V^T: d = off>>8 (256B rows), swizzle XORs bits 4-6 only
      const int d = off >> 8;
      const int esw = ((off & 255) ^ fsw(d)) >> 1;
      gload_lds16(Vg + (size_t)d * SEQLEN + esw, buf + 16384 + c * 1024);
    }
  }
}

__global__ __launch_bounds__(256)
void attn_fwd_kernel(const uint16_t* __restrict__ Qp, const uint16_t* __restrict__ Kp,
                     const uint16_t* __restrict__ VTp, uint16_t* __restrict__ Op) {
  __shared__ __align__(16) char lds[65536];  // 2 bufs x (K 16KB | V^T 16KB)
  const int tid = threadIdx.x;
  const int wave = tid >> 6, lane = tid & 63;
  const int l31 = lane & 31, hi = lane >> 5;
  const int bb = blockIdx.z, h = blockIdx.y;
  const int q0 = blockIdx.x * 128;

  // Q (pre-scaled) in registers: qf[ds] = Q[qrow][ds*16 + hi*8 .. +8].
  const int qrow = q0 + wave * 32 + l31;
  const uint16_t* qb = Qp + ((size_t)(bb * SEQLEN + qrow)) * DM + h * DKH;
  bf16x8 qf[4];
#pragma unroll
  for (int ds = 0; ds < 4; ++ds)
    qf[ds] = *(const bf16x8*)(qb + ds * 16 + hi * 8);

  bf16x8 onesf;
#pragma unroll
  for (int j = 0; j < 8; ++j) onesf[j] = (short)0x3F80;  // bf16 1.0

  f32x16 oacc[2], lacc, zero16;
#pragma unroll
  for (int r = 0; r < 16; ++r) { oacc[0][r] = 0.f; oacc[1][r] = 0.f; lacc[r] = 0.f; zero16[r] = 0.f; }
  float mrow = -1e30f;

  const uint16_t* Kg = Kp + ((size_t)(bb * SEQLEN)) * DM + h * DKH;
  const uint16_t* Vg = VTp + ((size_t)((bb * NHEAD + h) * DKH)) * SEQLEN;

  stage_kv(Kg, Vg, lds, wave, lane);  // tile 0 -> buf 0

  const int NT = SEQLEN / 128;  // 16
  for (int t = 0; t < NT; ++t) {
    __syncthreads();  // tile t resident (vmcnt drained); buf t+1 free
    if (t + 1 < NT)
      stage_kv(Kg + (size_t)(t + 1) * 128 * DM, Vg + (t + 1) * 128,
               lds + ((t + 1) & 1) * 32768, wave, lane);
    const char* kb = lds + (t & 1) * 32768;
    const char* vb = kb + 16384;

    // S^T = K Q^T via 32x32x16 (16 MFMA over 4 k-blocks of 32 rows).
    f32x16 sacc[4];
    __builtin_amdgcn_s_setprio(1);
#pragma unroll
    for (int n = 0; n < 4; ++n) {
      const int kr = 32 * n + l31;
      const char* krow = kb + kr * 128;
      const int f = fsw(kr);
      const bf16x8 kf0 = *(const bf16x8*)(krow + ((0 * 32 + hi * 16) ^ f));
      sacc[n] = __builtin_amdgcn_mfma_f32_32x32x16_bf16(kf0, qf[0], zero16, 0, 0, 0);
#pragma unroll
      for (int ds = 1; ds < 4; ++ds) {
        const bf16x8 kf = *(const bf16x8*)(krow + ((ds * 32 + hi * 16) ^ f));
        sacc[n] = __builtin_amdgcn_mfma_f32_32x32x16_bf16(kf, qf[ds], sacc[n], 0, 0, 0);
      }
    }
    __builtin_amdgcn_s_setprio(0);

    // Max-reduce: independent per-block max3 trees, then combine + 1 shfl.
    float bm[4];
#pragma unroll
    for (int n = 0; n < 4; ++n) {
      float m0 = max3f(sacc[n][0], sacc[n][1], sacc[n][2]);
      m0 = max3f(m0, sacc[n][3], sacc[n][4]);
      m0 = max3f(m0, sacc[n][5], sacc[n][6]);
      m0 = max3f(m0, sacc[n][7], sacc[n][8]);
      m0 = max3f(m0, sacc[n][9], sacc[n][10]);
      m0 = max3f(m0, sacc[n][11], sacc[n][12]);
      m0 = max3f(m0, sacc[n][13], sacc[n][14]);
      bm[n] = fmaxf(m0, sacc[n][15]);
    }
    float mx = max3f(fmaxf(bm[0], bm[1]), bm[2], bm[3]);
    mx = fmaxf(mx, __shfl_xor(mx, 32, 64));

    float mnew = mrow;
    if (__any(mx > mrow + 8.f)) {  // defer-max THR=8 (P bounded by 2^8)
      mnew = fmaxf(mrow, mx);
      const float scl = exp2_fast(mrow - mnew);
#pragma unroll
      for (int m = 0; m < 2; ++m)
#pragma unroll
        for (int r = 0; r < 16; ++r) oacc[m][r] *= scl;
      lacc[0] *= scl;
    }
    mrow = mnew;

#pragma unroll
    for (int n = 0; n < 4; ++n) {
      float pv[16];
#pragma unroll
      for (int r = 0; r < 16; ++r) pv[r] = exp2_fast(sacc[n][r] - mnew);
      // In-register P->bf16 fragments (T12): cvt_pk pairs + permlane32_swap
      // assemble contiguous k 0..15 (f0) / 16..31 (f1) B-fragments.
      const uint32_t c0 = cvtpk(pv[0], pv[1]),   c1 = cvtpk(pv[2], pv[3]);
      const uint32_t c2 = cvtpk(pv[4], pv[5]),   c3 = cvtpk(pv[6], pv[7]);
      const uint32_t c4 = cvtpk(pv[8], pv[9]),   c5 = cvtpk(pv[10], pv[11]);
      const uint32_t c6 = cvtpk(pv[12], pv[13]), c7 = cvtpk(pv[14], pv[15]);
      const u32x2 r02 = __builtin_amdgcn_permlane32_swap(c0, c2, false, false);
      const u32x2 r13 = __builtin_amdgcn_permlane32_swap(c1, c3, false, false);
      const u32x2 r46 = __builtin_amdgcn_permlane32_swap(c4, c6, false, false);
      const u32x2 r57 = __builtin_amdgcn_permlane32_swap(c5, c7, false, false);
      union { uint32_t w[4]; bf16x8 v; } f0, f1;
      f0.w[0] = r02.x; f0.w[1] = r13.x; f0.w[2] = r02.y; f0.w[3] = r13.y;
      f1.w[0] = r46.x; f1.w[1] = r57.x; f1.w[2] = r46.y; f1.w[3] = r57.y;

      // O^T += V^T P^T; l += 1^T P^T (row-sum on the MFMA pipe).
      __builtin_amdgcn_s_setprio(1);
#pragma unroll
      for (int m = 0; m < 2; ++m) {
        const int vr = 32 * m + l31;
        const char* vrow = vb + vr * 256;
        const int f = fsw(vr);
        const bf16x8 v0 = *(const bf16x8*)(vrow + ((n * 64 + hi * 16) ^ f));
        const bf16x8 v1 = *(const bf16x8*)(vrow + ((n * 64 + 32 + hi * 16) ^ f));
        oacc[m] = __builtin_amdgcn_mfma_f32_32x32x16_bf16(v0, f0.v, oacc[m], 0, 0, 0);
        oacc[m] = __builtin_amdgcn_mfma_f32_32x32x16_bf16(v1, f1.v, oacc[m], 0, 0, 0);
      }
      lacc = __builtin_amdgcn_mfma_f32_32x32x16_bf16(onesf, f0.v, lacc, 0, 0, 0);
      lacc = __builtin_amdgcn_mfma_f32_32x32x16_bf16(onesf, f1.v, lacc, 0, 0, 0);
      __builtin_amdgcn_s_setprio(0);
    }
  }

  // Normalize + store. oacc[m][r] = O^T[d][q=l31], d = 32m+(r&3)+8(r>>2)+4hi.
  const float il = 1.0f / lacc[0];
  uint16_t* ob = Op + ((size_t)(bb * SEQLEN + qrow)) * DM + h * DKH;
#pragma unroll
  for (int m = 0; m < 2; ++m)
#pragma unroll
    for (int rq = 0; rq < 4; ++rq) {
      const uint32_t w0 = cvtpk(oacc[m][4 * rq + 0] * il, oacc[m][4 * rq + 1] * il);
      const uint32_t w1 = cvtpk(oacc[m][4 * rq + 2] * il, oacc[m][4 * rq + 3] * il);
      *(uint64_t*)(ob + 32 * m + 8 * rq + 4 * hi) =
          (uint64_t)w0 | ((uint64_t)w1 << 32);
    }
}

extern "C" void kernel_launch(void* const* d_in, const int* in_sizes, int n_in,
                              void* d_out, int out_size, void* d_ws, size_t ws_size,
                              hipStream_t stream) {
  (void)in_sizes; (void)n_in; (void)out_size; (void)ws_size;
  const float* query = (const float*)d_in[0];
  const float* key_i = (const float*)d_in[1];
  const float* value = (const float*)d_in[2];
  const float* Wq = (const float*)d_in[3];
  const float* bq = (const float*)d_in[4];
  const float* Wk = (const float*)d_in[5];
  const float* bk = (const float*)d_in[6];
  const float* Wv = (const float*)d_in[7];
  const float* bv = (const float*)d_in[8];
  const float* Wo = (const float*)d_in[9];
  const float* bo = (const float*)d_in[10];
  float* out = (float*)d_out;

  char* ws = (char*)d_ws;
  const size_t MB = 1ull << 20;
  uint16_t* xq  = (uint16_t*)(ws + 0 * MB);    // 8 MB each (4096x1024 bf16)
  uint16_t* xk  = (uint16_t*)(ws + 8 * MB);
  uint16_t* xv  = (uint16_t*)(ws + 16 * MB);
  uint16_t* wqkv = (uint16_t*)(ws + 24 * MB);  // 3 x 2 MB contiguous (q,k,v)
  uint16_t* wob = (uint16_t*)(ws + 30 * MB);
  uint16_t* Qp  = (uint16_t*)(ws + 32 * MB);   // [s][dm], Q pre-scaled
  uint16_t* Kp  = (uint16_t*)(ws + 40 * MB);   // [s][dm]
  uint16_t* VTp = (uint16_t*)(ws + 48 * MB);   // [b,h,d,s]
  uint16_t* AO  = (uint16_t*)(ws + 56 * MB);   // [s][dm], ends at 64 MB

  const int n4x = (MTOT * DM) / 4;
  const int n4w = (DM * DM) / 4;
  CvtArgs ca;
  ca.src[0] = query; ca.dst[0] = xq;
  ca.src[1] = key_i; ca.dst[1] = xk;
  ca.src[2] = value; ca.dst[2] = xv;
  ca.src[3] = Wq;    ca.dst[3] = wqkv;
  ca.src[4] = Wk;    ca.dst[4] = wqkv + DM * DM;
  ca.src[5] = Wv;    ca.dst[5] = wqkv + 2 * DM * DM;
  ca.src[6] = Wo;    ca.dst[6] = wob;
  int acc = 0;
  for (int j = 0; j < 7; ++j) { acc += (j < 3) ? n4x : n4w; ca.end4[j] = acc; }
  const int blk = 256;
  cvt_all_kernel<<<(acc + blk - 1) / blk, blk, 0, stream>>>(ca);

  dim3 gq(MTOT / 128, 24);  // 32 x 24 = 768 blocks, 3 projections fused
  gemm_qkv<<<gq, 256, 0, stream>>>(xq, xk, xv, wqkv, bq, bk, bv, Qp, Kp, VTp);

  dim3 ga(SEQLEN / 128, NHEAD, NBATCH);  // 16 x 16 x 2 = 512 blocks
  attn_fwd_kernel<<<ga, 256, 0, stream>>>(Qp, Kp, VTp, AO);

  dim3 gg(MTOT / 128, DM / 128);  // 32 x 8
  gemm_out<<<gg, 256, 0, stream>>>(AO, wob, bo, out);
}